// Round 1
// baseline (313.102 us; speedup 1.0000x reference)
//
#include <hip/hip_runtime.h>
#include <math.h>

#define DMODEL 1024
#define NHEADS 16
#define DHEAD 64
#define SEQL 2048
#define NBATCH 2
#define MROWS (NBATCH*SEQL)   // 4096
#define NQKV (3*DMODEL)       // 3072

typedef __attribute__((ext_vector_type(8))) short bf8;
typedef __attribute__((ext_vector_type(4))) float f4;

__device__ __forceinline__ unsigned short f2b(float f) {
  union { float f; unsigned int u; } v; v.f = f;
  unsigned int r = v.u + 0x7FFFu + ((v.u >> 16) & 1u);
  return (unsigned short)(r >> 16);
}

__device__ __forceinline__ f4 mfma16(bf8 a, bf8 b, f4 c) {
  return __builtin_amdgcn_mfma_f32_16x16x32_bf16(a, b, c, 0, 0, 0);
}

// ---------------- pack kernels ----------------

__global__ __launch_bounds__(256) void k_f32_to_bf16(const float* __restrict__ in,
                                                     unsigned short* __restrict__ out, int n4) {
  int i = blockIdx.x * 256 + threadIdx.x;
  if (i < n4) {
    float4 v = ((const float4*)in)[i];
    ushort4 o;
    o.x = f2b(v.x); o.y = f2b(v.y); o.z = f2b(v.z); o.w = f2b(v.w);
    ((ushort4*)out)[i] = o;
  }
}

// W_Q/W_K/W_V [h][d][e] -> Wt[c][d] (c = p*1024 + h*64 + e), bf16, row-major over d
__global__ __launch_bounds__(256) void k_pack_wqkv(
    const float* __restrict__ Wq, const float* __restrict__ Wk, const float* __restrict__ Wv,
    const float* __restrict__ bq, const float* __restrict__ bk, const float* __restrict__ bv,
    unsigned short* __restrict__ Wt, float* __restrict__ biasq) {
  __shared__ float tile[64][65];
  int tid = threadIdx.x;
  int dt = blockIdx.x, h = blockIdx.y, p = blockIdx.z;
  const float* W = (p == 0) ? Wq : ((p == 1) ? Wk : Wv);
  #pragma unroll
  for (int j = 0; j < 16; j++) {
    int idx = tid + j * 256;
    int dd = idx >> 6, e = idx & 63;
    tile[dd][e] = W[(size_t)(h * DMODEL + dt * 64 + dd) * DHEAD + e];
  }
  __syncthreads();
  #pragma unroll
  for (int j = 0; j < 16; j++) {
    int idx = tid + j * 256;
    int e = idx >> 6, dd = idx & 63;
    Wt[(size_t)(p * DMODEL + h * 64 + e) * DMODEL + dt * 64 + dd] = f2b(tile[dd][e]);
  }
  if (dt == 0 && tid < 64) {
    const float* bsel = (p == 0) ? bq : ((p == 1) ? bk : bv);
    biasq[p * DMODEL + h * 64 + tid] = bsel[h * 64 + tid];
  }
}

// W_O [he][dm] -> Wot[dm][he] bf16
__global__ __launch_bounds__(256) void k_pack_wo(const float* __restrict__ Wo,
                                                 unsigned short* __restrict__ Wot) {
  __shared__ float tile[64][65];
  int tid = threadIdx.x;
  int het = blockIdx.x, dmt = blockIdx.y;
  #pragma unroll
  for (int j = 0; j < 16; j++) {
    int idx = tid + j * 256;
    int r = idx >> 6, c = idx & 63;
    tile[r][c] = Wo[(size_t)(het * 64 + r) * DMODEL + dmt * 64 + c];
  }
  __syncthreads();
  #pragma unroll
  for (int j = 0; j < 16; j++) {
    int idx = tid + j * 256;
    int rr = idx >> 6, cc = idx & 63;
    Wot[(size_t)(dmt * 64 + rr) * DMODEL + het * 64 + cc] = f2b(tile[cc][rr]);
  }
}

// ---------------- GEMM: C[4096][N] = A[4096][K] * Bt[N][K]^T + bias ----------------

template<int N, int K, bool OUTF32>
__global__ __launch_bounds__(256) void k_gemm_bt(
    const unsigned short* __restrict__ A, const unsigned short* __restrict__ Bt,
    const float* __restrict__ bias, void* __restrict__ Cp) {
  constexpr int LDSS = 40;  // 32 + 8 pad -> 80B row stride, 2-way bank alias (free)
  __shared__ unsigned short As[128 * LDSS];
  __shared__ unsigned short Bs[128 * LDSS];
  int tid = threadIdx.x;
  int lane = tid & 63, w = tid >> 6;
  int wr = w >> 1, wc = w & 1;
  int lr = lane & 15, lg = lane >> 4;
  int m0 = blockIdx.x * 128, n0 = blockIdx.y * 128;
  f4 acc[4][4] = {};
  for (int k0 = 0; k0 < K; k0 += 32) {
    #pragma unroll
    for (int cc = 0; cc < 2; cc++) {
      int c = tid + cc * 256;
      int row = c >> 2, col = (c & 3) * 8;
      *(int4*)(&As[row * LDSS + col]) = *(const int4*)(&A[(size_t)(m0 + row) * K + k0 + col]);
      *(int4*)(&Bs[row * LDSS + col]) = *(const int4*)(&Bt[(size_t)(n0 + row) * K + k0 + col]);
    }
    __syncthreads();
    bf8 af[4], bfv[4];
    #pragma unroll
    for (int i = 0; i < 4; i++) {
      af[i]  = *(const bf8*)(&As[(wr * 64 + i * 16 + lr) * LDSS + lg * 8]);
      bfv[i] = *(const bf8*)(&Bs[(wc * 64 + i * 16 + lr) * LDSS + lg * 8]);
    }
    #pragma unroll
    for (int i = 0; i < 4; i++)
      #pragma unroll
      for (int j = 0; j < 4; j++)
        acc[i][j] = mfma16(af[i], bfv[j], acc[i][j]);
    __syncthreads();
  }
  #pragma unroll
  for (int i = 0; i < 4; i++)
    #pragma unroll
    for (int j = 0; j < 4; j++) {
      int col = n0 + wc * 64 + j * 16 + lr;
      float bv = bias[col];
      #pragma unroll
      for (int r = 0; r < 4; r++) {
        int row = m0 + wr * 64 + i * 16 + lg * 4 + r;
        float v = acc[i][j][r] + bv;
        if (OUTF32) ((float*)Cp)[(size_t)row * N + col] = v;
        else ((unsigned short*)Cp)[(size_t)row * N + col] = f2b(v);
      }
    }
}

// ---------------- flash attention ----------------
// qkv: [4096][3072] bf16 (q | k | v blocks of 1024 cols, head h at h*64)
// zb : [4096][1024] bf16  (cols = h*64 + e)

__global__ __launch_bounds__(256) void k_attn(const unsigned short* __restrict__ qkv,
                                              unsigned short* __restrict__ zb) {
  constexpr int KP = 88;  // 176B row stride: 16B-aligned b128 reads, ~2-way banks
  __shared__ unsigned short Ks[64 * KP];
  __shared__ unsigned short Vt[64 * KP];
  __shared__ unsigned short Pl[4][32 * KP];
  int tid = threadIdx.x;
  int lane = tid & 63, w = tid >> 6;
  int lr = lane & 15, lg = lane >> 4;
  int q0 = blockIdx.x * 128;
  int bh = blockIdx.y;
  int b = bh >> 4, h = bh & 15;
  int qw = q0 + w * 32;
  const size_t rowbase = (size_t)b * SEQL;

  bf8 qf_[2][2];
  #pragma unroll
  for (int i = 0; i < 2; i++)
    #pragma unroll
    for (int kd = 0; kd < 2; kd++)
      qf_[i][kd] = *(const bf8*)(&qkv[(rowbase + qw + i * 16 + lr) * NQKV + h * DHEAD + kd * 32 + lg * 8]);

  f4 accz[2][4] = {};
  float m_[2][4], l_[2][4];
  #pragma unroll
  for (int i = 0; i < 2; i++)
    #pragma unroll
    for (int r = 0; r < 4; r++) { m_[i][r] = -1e30f; l_[i][r] = 0.f; }

  int nkv = (q0 + 128) >> 6;
  for (int t = 0; t < nkv; t++) {
    int kv0 = t << 6;
    // stage K (row-major) and V (transposed) into LDS
    #pragma unroll
    for (int cc = 0; cc < 2; cc++) {
      int c = tid + cc * 256;
      int kv = c >> 3, dc = (c & 7) * 8;
      *(int4*)(&Ks[kv * KP + dc]) =
          *(const int4*)(&qkv[(rowbase + kv0 + kv) * NQKV + DMODEL + h * DHEAD + dc]);
      int4 vvi = *(const int4*)(&qkv[(rowbase + kv0 + kv) * NQKV + 2 * DMODEL + h * DHEAD + dc]);
      const unsigned short* vv = (const unsigned short*)&vvi;
      #pragma unroll
      for (int i = 0; i < 8; i++) Vt[(dc + i) * KP + kv] = vv[i];
    }
    __syncthreads();
    if (kv0 <= qw + 31) {   // wave-uniform: skip fully-masked tiles
      f4 s[2][4] = {};
      #pragma unroll
      for (int kd = 0; kd < 2; kd++) {
        bf8 kf_[4];
        #pragma unroll
        for (int j = 0; j < 4; j++)
          kf_[j] = *(const bf8*)(&Ks[(j * 16 + lr) * KP + kd * 32 + lg * 8]);
        #pragma unroll
        for (int i = 0; i < 2; i++)
          #pragma unroll
          for (int j = 0; j < 4; j++)
            s[i][j] = mfma16(qf_[i][kd], kf_[j], s[i][j]);
      }
      // scale + causal mask (S layout: row = qw+i*16+lg*4+r, col = kv0+j*16+lr)
      #pragma unroll
      for (int i = 0; i < 2; i++)
        #pragma unroll
        for (int j = 0; j < 4; j++)
          #pragma unroll
          for (int r = 0; r < 4; r++) {
            int row = qw + i * 16 + lg * 4 + r;
            int col = kv0 + j * 16 + lr;
            float sv = s[i][j][r] * 0.125f;
            s[i][j][r] = (col > row) ? -1e30f : sv;
          }
      // online softmax: row lives in the 16 lanes sharing lg
      #pragma unroll
      for (int i = 0; i < 2; i++)
        #pragma unroll
        for (int r = 0; r < 4; r++) {
          float mx = fmaxf(fmaxf(s[i][0][r], s[i][1][r]), fmaxf(s[i][2][r], s[i][3][r]));
          #pragma unroll
          for (int d = 1; d < 16; d <<= 1) mx = fmaxf(mx, __shfl_xor(mx, d));
          float mn = fmaxf(m_[i][r], mx);
          float al = __expf(m_[i][r] - mn);
          m_[i][r] = mn;
          l_[i][r] *= al;
          #pragma unroll
          for (int e = 0; e < 4; e++) accz[i][e][r] *= al;
          float rs = 0.f;
          #pragma unroll
          for (int j = 0; j < 4; j++) {
            float pv = __expf(s[i][j][r] - mn);
            s[i][j][r] = pv;
            rs += pv;
          }
          #pragma unroll
          for (int d = 1; d < 16; d <<= 1) rs += __shfl_xor(rs, d);
          l_[i][r] += rs;
        }
      // P -> LDS (per-wave region, no barrier needed)
      #pragma unroll
      for (int i = 0; i < 2; i++)
        #pragma unroll
        for (int j = 0; j < 4; j++)
          #pragma unroll
          for (int r = 0; r < 4; r++)
            Pl[w][(i * 16 + lg * 4 + r) * KP + j * 16 + lr] = f2b(s[i][j][r]);
      // PV: Z[q][e] += P[q][kv] * V[kv][e]
      #pragma unroll
      for (int ks = 0; ks < 2; ks++) {
        bf8 pa[2], vb[4];
        #pragma unroll
        for (int i = 0; i < 2; i++)
          pa[i] = *(const bf8*)(&Pl[w][(i * 16 + lr) * KP + ks * 32 + lg * 8]);
        #pragma unroll
        for (int e = 0; e < 4; e++)
          vb[e] = *(const bf8*)(&Vt[(e * 16 + lr) * KP + ks * 32 + lg * 8]);
        #pragma unroll
        for (int i = 0; i < 2; i++)
          #pragma unroll
          for (int e = 0; e < 4; e++)
            accz[i][e] = mfma16(pa[i], vb[e], accz[i][e]);
      }
    }
    __syncthreads();
  }
  // epilogue: z = accz / l
  #pragma unroll
  for (int i = 0; i < 2; i++)
    #pragma unroll
    for (int r = 0; r < 4; r++) {
      float inv = 1.0f / l_[i][r];
      size_t row = rowbase + qw + i * 16 + lg * 4 + r;
      #pragma unroll
      for (int e = 0; e < 4; e++)
        zb[row * DMODEL + h * DHEAD + e * 16 + lr] = f2b(accz[i][e][r] * inv);
    }
}

// ---------------- launch ----------------

extern "C" void kernel_launch(void* const* d_in, const int* in_sizes, int n_in,
                              void* d_out, int out_size, void* d_ws, size_t ws_size,
                              hipStream_t stream) {
  const float* x  = (const float*)d_in[0];
  const float* Wq = (const float*)d_in[1];
  const float* bq = (const float*)d_in[2];
  const float* Wk = (const float*)d_in[3];
  const float* bk = (const float*)d_in[4];
  const float* Wv = (const float*)d_in[5];
  const float* bv = (const float*)d_in[6];
  const float* Wo = (const float*)d_in[7];
  const float* bo = (const float*)d_in[8];

  char* ws = (char*)d_ws;
  // layout: xb 8MiB | wqkvt 6MiB | biasq 16KiB | qkv 24MiB | wot 2MiB  (~40MiB)
  unsigned short* xb    = (unsigned short*)(ws);
  unsigned short* wqkvt = (unsigned short*)(ws + 8388608);
  float*          biasq = (float*)(ws + 8388608 + 6291456);
  unsigned short* qkv   = (unsigned short*)(ws + 8388608 + 6291456 + 16384);
  unsigned short* wot   = (unsigned short*)(ws + 8388608 + 6291456 + 16384 + 25165824);
  unsigned short* zbuf  = xb;  // alias: xb dead after GEMM1, attn runs after (stream-ordered)

  k_f32_to_bf16<<<(MROWS * DMODEL / 4 + 255) / 256, 256, 0, stream>>>(x, xb, MROWS * DMODEL / 4);
  k_pack_wqkv<<<dim3(16, 16, 3), 256, 0, stream>>>(Wq, Wk, Wv, bq, bk, bv, wqkvt, biasq);
  k_pack_wo<<<dim3(16, 16), 256, 0, stream>>>(Wo, wot);
  k_gemm_bt<NQKV, DMODEL, false><<<dim3(32, 24), 256, 0, stream>>>(xb, wqkvt, biasq, qkv);
  k_attn<<<dim3(16, 32), 256, 0, stream>>>(qkv, zbuf);
  k_gemm_bt<DMODEL, DMODEL, true><<<dim3(32, 8), 256, 0, stream>>>(zbuf, wot, bo, (float*)d_out);
}

// Round 6
// 247.414 us; speedup vs baseline: 1.2655x; 1.2655x over previous
//
#include <hip/hip_runtime.h>
#include <math.h>

#define DMODEL 1024
#define NHEADS 16
#define DHEAD 64
#define SEQL 2048
#define NBATCH 2
#define MROWS (NBATCH*SEQL)   // 4096
#define NQKV (3*DMODEL)       // 3072

typedef __attribute__((ext_vector_type(8))) short bf8;
typedef __attribute__((ext_vector_type(4))) float f4;

__device__ __forceinline__ unsigned short f2b(float f) {
  union { float f; unsigned int u; } v; v.f = f;
  unsigned int r = v.u + 0x7FFFu + ((v.u >> 16) & 1u);
  return (unsigned short)(r >> 16);
}

__device__ __forceinline__ f4 mfma16(bf8 a, bf8 b, f4 c) {
  return __builtin_amdgcn_mfma_f32_16x16x32_bf16(a, b, c, 0, 0, 0);
}

__device__ __forceinline__ void gload16(const void* g, void* l) {
  __builtin_amdgcn_global_load_lds(
      (const __attribute__((address_space(1))) unsigned int*)g,
      (__attribute__((address_space(3))) unsigned int*)l, 16, 0, 0);
}

// ---------------- pack kernels ----------------

__global__ __launch_bounds__(256) void k_f32_to_bf16(const float* __restrict__ in,
                                                     unsigned short* __restrict__ out, int n4) {
  int i = blockIdx.x * 256 + threadIdx.x;
  if (i < n4) {
    float4 v = ((const float4*)in)[i];
    ushort4 o;
    o.x = f2b(v.x); o.y = f2b(v.y); o.z = f2b(v.z); o.w = f2b(v.w);
    ((ushort4*)out)[i] = o;
  }
}

// W_Q/W_K/W_V [h][d][e] -> Wt[c][d] (c = p*1024 + h*64 + e), bf16, row-major over d
__global__ __launch_bounds__(256) void k_pack_wqkv(
    const float* __restrict__ Wq, const float* __restrict__ Wk, const float* __restrict__ Wv,
    const float* __restrict__ bq, const float* __restrict__ bk, const float* __restrict__ bv,
    unsigned short* __restrict__ Wt, float* __restrict__ biasq) {
  __shared__ float tile[64][65];
  int tid = threadIdx.x;
  int dt = blockIdx.x, h = blockIdx.y, p = blockIdx.z;
  const float* W = (p == 0) ? Wq : ((p == 1) ? Wk : Wv);
  #pragma unroll
  for (int j = 0; j < 16; j++) {
    int idx = tid + j * 256;
    int dd = idx >> 6, e = idx & 63;
    tile[dd][e] = W[(size_t)(h * DMODEL + dt * 64 + dd) * DHEAD + e];
  }
  __syncthreads();
  #pragma unroll
  for (int j = 0; j < 16; j++) {
    int idx = tid + j * 256;
    int e = idx >> 6, dd = idx & 63;
    Wt[(size_t)(p * DMODEL + h * 64 + e) * DMODEL + dt * 64 + dd] = f2b(tile[dd][e]);
  }
  if (dt == 0 && tid < 64) {
    const float* bsel = (p == 0) ? bq : ((p == 1) ? bk : bv);
    biasq[p * DMODEL + h * 64 + tid] = bsel[h * 64 + tid];
  }
}

// W_O [he][dm] -> Wot[dm][he] bf16
__global__ __launch_bounds__(256) void k_pack_wo(const float* __restrict__ Wo,
                                                 unsigned short* __restrict__ Wot) {
  __shared__ float tile[64][65];
  int tid = threadIdx.x;
  int het = blockIdx.x, dmt = blockIdx.y;
  #pragma unroll
  for (int j = 0; j < 16; j++) {
    int idx = tid + j * 256;
    int r = idx >> 6, c = idx & 63;
    tile[r][c] = Wo[(size_t)(het * 64 + r) * DMODEL + dmt * 64 + c];
  }
  __syncthreads();
  #pragma unroll
  for (int j = 0; j < 16; j++) {
    int idx = tid + j * 256;
    int rr = idx >> 6, cc = idx & 63;
    Wot[(size_t)(dmt * 64 + rr) * DMODEL + het * 64 + cc] = f2b(tile[cc][rr]);
  }
}

// ---------------- GEMM: C[4096][N] = A[4096][K] * Bt[N][K]^T + bias ----------------
// m97 structure: BK=64, linear LDS via global_load_lds(16B) with pre-swizzled
// source (chunk ^= row&7), conflict-free swizzled ds_read_b128.

template<int N, int K, bool OUTF32>
__global__ __launch_bounds__(256) void k_gemm_bt(
    const unsigned short* __restrict__ A, const unsigned short* __restrict__ Bt,
    const float* __restrict__ bias, void* __restrict__ Cp) {
  __shared__ unsigned short As[128 * 64];
  __shared__ unsigned short Bs[128 * 64];
  int tid = threadIdx.x;
  int lane = tid & 63, w = tid >> 6;
  int wr = w >> 1, wc = w & 1;
  int lr = lane & 15, lg = lane >> 4;
  int m0 = blockIdx.x * 128, n0 = blockIdx.y * 128;
  // staging geometry: LDS dest chunk (16B) idx = it*256 + w*64 + lane
  // -> row = idx>>3, lds chunk-in-row = lane&7, global chunk = (lane&7)^(row&7)
  int srow = w * 8 + (lane >> 3);               // + it*32
  int scol = ((lane & 7) ^ (lane >> 3)) * 8;    // row&7 == lane>>3 here
  f4 acc[4][4] = {};
  for (int k0 = 0; k0 < K; k0 += 64) {
    #pragma unroll
    for (int it = 0; it < 4; it++) {
      int row = it * 32 + srow;
      gload16(&A[(size_t)(m0 + row) * K + k0 + scol], &As[(it * 256 + w * 64) * 8]);
      gload16(&Bt[(size_t)(n0 + row) * K + k0 + scol], &Bs[(it * 256 + w * 64) * 8]);
    }
    __syncthreads();
    #pragma unroll
    for (int kk = 0; kk < 2; kk++) {
      bf8 af[4], bfv[4];
      #pragma unroll
      for (int i = 0; i < 4; i++) {
        int ra = wr * 64 + i * 16 + lr;
        int rb = wc * 64 + i * 16 + lr;
        af[i]  = *(const bf8*)(&As[ra * 64 + (((kk * 4 + lg) ^ (ra & 7)) * 8)]);
        bfv[i] = *(const bf8*)(&Bs[rb * 64 + (((kk * 4 + lg) ^ (rb & 7)) * 8)]);
      }
      #pragma unroll
      for (int i = 0; i < 4; i++)
        #pragma unroll
        for (int j = 0; j < 4; j++)
          acc[i][j] = mfma16(af[i], bfv[j], acc[i][j]);
    }
    __syncthreads();
  }
  #pragma unroll
  for (int i = 0; i < 4; i++)
    #pragma unroll
    for (int j = 0; j < 4; j++) {
      int col = n0 + wc * 64 + j * 16 + lr;
      float bv = bias[col];
      #pragma unroll
      for (int r = 0; r < 4; r++) {
        int row = m0 + wr * 64 + i * 16 + lg * 4 + r;
        float v = acc[i][j][r] + bv;
        if (OUTF32) ((float*)Cp)[(size_t)row * N + col] = v;
        else ((unsigned short*)Cp)[(size_t)row * N + col] = f2b(v);
      }
    }
}

// ---------------- flash attention ----------------
// qkv: [4096][3072] bf16 (q | k | v blocks of 1024 cols, head h at h*64)
// zb : [4096][1024] bf16  (cols = h*64 + e)
// Causal balance: block handles q-tiles {tlo, 31-tlo} (64 rows each) so every
// block does exactly 33 row-tile x kv-tile units of MFMA work.

#define KP 72
#define SWZ(r, c) ((r) * KP + ((c) ^ ((((r) >> 3) & 7) << 3)))

__global__ __launch_bounds__(256) void k_attn(const unsigned short* __restrict__ qkv,
                                              unsigned short* __restrict__ zb) {
  __shared__ unsigned short Ks[64 * KP];
  __shared__ unsigned short Vt[64 * KP];
  __shared__ unsigned short Pl[4][32 * KP];
  int tid = threadIdx.x;
  int lane = tid & 63, w = tid >> 6;
  int lr = lane & 15, lg = lane >> 4;
  int tlo = blockIdx.x;         // 0..15
  int thi = 31 - tlo;           // 16..31
  int bh = blockIdx.y;
  int b = bh >> 4, h = bh & 15;
  int qb[2] = { tlo * 64 + w * 16, thi * 64 + w * 16 };
  const size_t rowbase = (size_t)b * SEQL;

  bf8 qf_[2][2];
  #pragma unroll
  for (int i = 0; i < 2; i++)
    #pragma unroll
    for (int kd = 0; kd < 2; kd++)
      qf_[i][kd] = *(const bf8*)(&qkv[(rowbase + qb[i] + lr) * NQKV + h * DHEAD + kd * 32 + lg * 8]);

  f4 accz[2][4] = {};
  float m_[2][4], l_[2][4];
  #pragma unroll
  for (int i = 0; i < 2; i++)
    #pragma unroll
    for (int r = 0; r < 4; r++) { m_[i][r] = -1e30f; l_[i][r] = 0.f; }

  int nkv = thi + 1;
  for (int tt = 0; tt < nkv; tt++) {
    int kv0 = tt << 6;
    // stage K and V(transposed) into LDS, both XOR-swizzled
    #pragma unroll
    for (int cc = 0; cc < 2; cc++) {
      int c = tid + cc * 256;
      int kv = c >> 3, dc = (c & 7) * 8;
      *(int4*)(&Ks[SWZ(kv, dc)]) =
          *(const int4*)(&qkv[(rowbase + kv0 + kv) * NQKV + DMODEL + h * DHEAD + dc]);
      int4 vvi = *(const int4*)(&qkv[(rowbase + kv0 + kv) * NQKV + 2 * DMODEL + h * DHEAD + dc]);
      const unsigned short* vv = (const unsigned short*)&vvi;
      #pragma unroll
      for (int i2 = 0; i2 < 8; i2++) Vt[SWZ(dc + i2, kv)] = vv[i2];
    }
    __syncthreads();
    bool act0 = (tt <= tlo);   // group 1 (high tile) is active on every staged tile
    f4 s[2][4] = {};
    #pragma unroll
    for (int kd = 0; kd < 2; kd++) {
      bf8 kf_[4];
      #pragma unroll
      for (int j = 0; j < 4; j++)
        kf_[j] = *(const bf8*)(&Ks[SWZ(j * 16 + lr, kd * 32 + lg * 8)]);
      #pragma unroll
      for (int i = 0; i < 2; i++) {
        if (i == 0 && !act0) continue;
        #pragma unroll
        for (int j = 0; j < 4; j++)
          s[i][j] = mfma16(qf_[i][kd], kf_[j], s[i][j]);
      }
    }
    // scale + causal mask + online softmax (row lives in the 16 lanes sharing lg)
    #pragma unroll
    for (int i = 0; i < 2; i++) {
      if (i == 0 && !act0) continue;
      #pragma unroll
      for (int j = 0; j < 4; j++)
        #pragma unroll
        for (int r = 0; r < 4; r++) {
          int row = qb[i] + lg * 4 + r;
          int col = kv0 + j * 16 + lr;
          float sv = s[i][j][r] * 0.125f;
          s[i][j][r] = (col > row) ? -1e30f : sv;
        }
      #pragma unroll
      for (int r = 0; r < 4; r++) {
        float mx = fmaxf(fmaxf(s[i][0][r], s[i][1][r]), fmaxf(s[i][2][r], s[i][3][r]));
        #pragma unroll
        for (int d = 1; d < 16; d <<= 1) mx = fmaxf(mx, __shfl_xor(mx, d));
        float mn = fmaxf(m_[i][r], mx);
        float al = __expf(m_[i][r] - mn);
        m_[i][r] = mn;
        l_[i][r] *= al;
        #pragma unroll
        for (int e = 0; e < 4; e++) accz[i][e][r] *= al;
        float rs = 0.f;
        #pragma unroll
        for (int j = 0; j < 4; j++) {
          float pv = __expf(s[i][j][r] - mn);
          s[i][j][r] = pv;
          rs += pv;
        }
        #pragma unroll
        for (int d = 1; d < 16; d <<= 1) rs += __shfl_xor(rs, d);
        l_[i][r] += rs;
      }
      // P -> LDS (per-wave region, swizzled; no barrier needed)
      #pragma unroll
      for (int j = 0; j < 4; j++)
        #pragma unroll
        for (int r = 0; r < 4; r++)
          Pl[w][SWZ(i * 16 + lg * 4 + r, j * 16 + lr)] = f2b(s[i][j][r]);
    }
    // PV: Z[q][e] += P[q][kv] * V[kv][e]
    #pragma unroll
    for (int ks = 0; ks < 2; ks++) {
      bf8 vb[4];
      #pragma unroll
      for (int e = 0; e < 4; e++)
        vb[e] = *(const bf8*)(&Vt[SWZ(e * 16 + lr, ks * 32 + lg * 8)]);
      #pragma unroll
      for (int i = 0; i < 2; i++) {
        if (i == 0 && !act0) continue;
        bf8 pa = *(const bf8*)(&Pl[w][SWZ(i * 16 + lr, ks * 32 + lg * 8)]);
        #pragma unroll
        for (int e = 0; e < 4; e++)
          accz[i][e] = mfma16(pa, vb[e], accz[i][e]);
      }
    }
    __syncthreads();
  }
  // epilogue: z = accz / l
  #pragma unroll
  for (int i = 0; i < 2; i++)
    #pragma unroll
    for (int r = 0; r < 4; r++) {
      float inv = 1.0f / l_[i][r];
      size_t row = rowbase + qb[i] + lg * 4 + r;
      #pragma unroll
      for (int e = 0; e < 4; e++)
        zb[row * DMODEL + h * DHEAD + e * 16 + lr] = f2b(accz[i][e][r] * inv);
    }
}

// ---------------- launch ----------------

extern "C" void kernel_launch(void* const* d_in, const int* in_sizes, int n_in,
                              void* d_out, int out_size, void* d_ws, size_t ws_size,
                              hipStream_t stream) {
  const float* x  = (const float*)d_in[0];
  const float* Wq = (const float*)d_in[1];
  const float* bq = (const float*)d_in[2];
  const float* Wk = (const float*)d_in[3];
  const float* bk = (const float*)d_in[4];
  const float* Wv = (const float*)d_in[5];
  const float* bv = (const float*)d_in[6];
  const float* Wo = (const float*)d_in[7];
  const float* bo = (const float*)d_in[8];

  char* ws = (char*)d_ws;
  // layout: xb 8MiB | wqkvt 6MiB | biasq 16KiB | qkv 24MiB | wot 2MiB  (~40MiB)
  unsigned short* xb    = (unsigned short*)(ws);
  unsigned short* wqkvt = (unsigned short*)(ws + 8388608);
  float*          biasq = (float*)(ws + 8388608 + 6291456);
  unsigned short* qkv   = (unsigned short*)(ws + 8388608 + 6291456 + 16384);
  unsigned short* wot   = (unsigned short*)(ws + 8388608 + 6291456 + 16384 + 25165824);
  unsigned short* zbuf  = xb;  // alias: xb dead after GEMM1 (stream-ordered)

  k_f32_to_bf16<<<(MROWS * DMODEL / 4 + 255) / 256, 256, 0, stream>>>(x, xb, MROWS * DMODEL / 4);
  k_pack_wqkv<<<dim3(16, 16, 3), 256, 0, stream>>>(Wq, Wk, Wv, bq, bk, bv, wqkvt, biasq);
  k_pack_wo<<<dim3(16, 16), 256, 0, stream>>>(Wo, wot);
  k_gemm_bt<NQKV, DMODEL, false><<<dim3(32, 24), 256, 0, stream>>>(xb, wqkvt, biasq, qkv);
  k_attn<<<dim3(16, 32), 256, 0, stream>>>(qkv, zbuf);
  k_gemm_bt<DMODEL, DMODEL, true><<<dim3(32, 8), 256, 0, stream>>>(zbuf, wot, bo, (float*)d_out);
}

// Round 7
// 232.152 us; speedup vs baseline: 1.3487x; 1.0657x over previous
//
#include <hip/hip_runtime.h>
#include <math.h>

#define DMODEL 1024
#define NHEADS 16
#define DHEAD 64
#define SEQL 2048
#define NBATCH 2
#define MROWS (NBATCH*SEQL)   // 4096
#define NQKV (3*DMODEL)       // 3072

typedef __attribute__((ext_vector_type(8))) short bf8;
typedef __attribute__((ext_vector_type(4))) float f4;
typedef __attribute__((ext_vector_type(16))) float f16v;

__device__ __forceinline__ unsigned short f2b(float f) {
  union { float f; unsigned int u; } v; v.f = f;
  unsigned int r = v.u + 0x7FFFu + ((v.u >> 16) & 1u);
  return (unsigned short)(r >> 16);
}

__device__ __forceinline__ f4 mfma16(bf8 a, bf8 b, f4 c) {
  return __builtin_amdgcn_mfma_f32_16x16x32_bf16(a, b, c, 0, 0, 0);
}

__device__ __forceinline__ f16v mfma32(bf8 a, bf8 b, f16v c) {
  return __builtin_amdgcn_mfma_f32_32x32x16_bf16(a, b, c, 0, 0, 0);
}

__device__ __forceinline__ unsigned cvtpk(float lo, float hi) {
  unsigned r;
  asm("v_cvt_pk_bf16_f32 %0, %1, %2" : "=v"(r) : "v"(lo), "v"(hi));
  return r;
}

__device__ __forceinline__ void gload16(const void* g, void* l) {
  __builtin_amdgcn_global_load_lds(
      (const __attribute__((address_space(1))) unsigned int*)g,
      (__attribute__((address_space(3))) unsigned int*)l, 16, 0, 0);
}

// ---------------- pack kernels ----------------

__global__ __launch_bounds__(256) void k_f32_to_bf16(const float* __restrict__ in,
                                                     unsigned short* __restrict__ out, int n4) {
  int i = blockIdx.x * 256 + threadIdx.x;
  if (i < n4) {
    float4 v = ((const float4*)in)[i];
    ushort4 o;
    o.x = f2b(v.x); o.y = f2b(v.y); o.z = f2b(v.z); o.w = f2b(v.w);
    ((ushort4*)out)[i] = o;
  }
}

// W_Q/W_K/W_V [h][d][e] -> Wt[c][d] (c = p*1024 + h*64 + e), bf16, row-major over d
__global__ __launch_bounds__(256) void k_pack_wqkv(
    const float* __restrict__ Wq, const float* __restrict__ Wk, const float* __restrict__ Wv,
    const float* __restrict__ bq, const float* __restrict__ bk, const float* __restrict__ bv,
    unsigned short* __restrict__ Wt, float* __restrict__ biasq) {
  __shared__ float tile[64][65];
  int tid = threadIdx.x;
  int dt = blockIdx.x, h = blockIdx.y, p = blockIdx.z;
  const float* W = (p == 0) ? Wq : ((p == 1) ? Wk : Wv);
  #pragma unroll
  for (int j = 0; j < 16; j++) {
    int idx = tid + j * 256;
    int dd = idx >> 6, e = idx & 63;
    tile[dd][e] = W[(size_t)(h * DMODEL + dt * 64 + dd) * DHEAD + e];
  }
  __syncthreads();
  #pragma unroll
  for (int j = 0; j < 16; j++) {
    int idx = tid + j * 256;
    int e = idx >> 6, dd = idx & 63;
    Wt[(size_t)(p * DMODEL + h * 64 + e) * DMODEL + dt * 64 + dd] = f2b(tile[dd][e]);
  }
  if (dt == 0 && tid < 64) {
    const float* bsel = (p == 0) ? bq : ((p == 1) ? bk : bv);
    biasq[p * DMODEL + h * 64 + tid] = bsel[h * 64 + tid];
  }
}

// W_O [he][dm] -> Wot[dm][he] bf16
__global__ __launch_bounds__(256) void k_pack_wo(const float* __restrict__ Wo,
                                                 unsigned short* __restrict__ Wot) {
  __shared__ float tile[64][65];
  int tid = threadIdx.x;
  int het = blockIdx.x, dmt = blockIdx.y;
  #pragma unroll
  for (int j = 0; j < 16; j++) {
    int idx = tid + j * 256;
    int r = idx >> 6, c = idx & 63;
    tile[r][c] = Wo[(size_t)(het * 64 + r) * DMODEL + dmt * 64 + c];
  }
  __syncthreads();
  #pragma unroll
  for (int j = 0; j < 16; j++) {
    int idx = tid + j * 256;
    int rr = idx >> 6, cc = idx & 63;
    Wot[(size_t)(dmt * 64 + rr) * DMODEL + het * 64 + cc] = f2b(tile[cc][rr]);
  }
}

// ---------------- GEMM: C[4096][N] = A[4096][K] * Bt[N][K]^T + bias ----------------

template<int N, int K, bool OUTF32>
__global__ __launch_bounds__(256) void k_gemm_bt(
    const unsigned short* __restrict__ A, const unsigned short* __restrict__ Bt,
    const float* __restrict__ bias, void* __restrict__ Cp) {
  __shared__ unsigned short As[128 * 64];
  __shared__ unsigned short Bs[128 * 64];
  int tid = threadIdx.x;
  int lane = tid & 63, w = tid >> 6;
  int wr = w >> 1, wc = w & 1;
  int lr = lane & 15, lg = lane >> 4;
  int m0 = blockIdx.x * 128, n0 = blockIdx.y * 128;
  int srow = w * 8 + (lane >> 3);               // + it*32
  int scol = ((lane & 7) ^ (lane >> 3)) * 8;    // row&7 == lane>>3 here
  f4 acc[4][4] = {};
  for (int k0 = 0; k0 < K; k0 += 64) {
    #pragma unroll
    for (int it = 0; it < 4; it++) {
      int row = it * 32 + srow;
      gload16(&A[(size_t)(m0 + row) * K + k0 + scol], &As[(it * 256 + w * 64) * 8]);
      gload16(&Bt[(size_t)(n0 + row) * K + k0 + scol], &Bs[(it * 256 + w * 64) * 8]);
    }
    __syncthreads();
    #pragma unroll
    for (int kk = 0; kk < 2; kk++) {
      bf8 af[4], bfv[4];
      #pragma unroll
      for (int i = 0; i < 4; i++) {
        int ra = wr * 64 + i * 16 + lr;
        int rb = wc * 64 + i * 16 + lr;
        af[i]  = *(const bf8*)(&As[ra * 64 + (((kk * 4 + lg) ^ (ra & 7)) * 8)]);
        bfv[i] = *(const bf8*)(&Bs[rb * 64 + (((kk * 4 + lg) ^ (rb & 7)) * 8)]);
      }
      #pragma unroll
      for (int i = 0; i < 4; i++)
        #pragma unroll
        for (int j = 0; j < 4; j++)
          acc[i][j] = mfma16(af[i], bfv[j], acc[i][j]);
    }
    __syncthreads();
  }
  #pragma unroll
  for (int i = 0; i < 4; i++)
    #pragma unroll
    for (int j = 0; j < 4; j++) {
      int col = n0 + wc * 64 + j * 16 + lr;
      float bv = bias[col];
      #pragma unroll
      for (int r = 0; r < 4; r++) {
        int row = m0 + wr * 64 + i * 16 + lg * 4 + r;
        float v = acc[i][j][r] + bv;
        if (OUTF32) ((float*)Cp)[(size_t)row * N + col] = v;
        else ((unsigned short*)Cp)[(size_t)row * N + col] = f2b(v);
      }
    }
}

// ---------------- flash attention (swapped-QK^T, 32x32 MFMA, P in registers) ----------------
// qkv: [4096][3072] bf16 (q | k | v blocks of 1024 cols, head h at h*64)
// zb : [4096][1024] bf16
// Per block: 4 waves x 32 q-rows = 128 q-rows. S^T = mfma32(K, Q): lane owns
// q-row (lane&31); its 32 k-values split across the (l, l+32) pair.
// Softmax: in-lane reduce + one shfl_xor(32). P -> PV A-frags via cvt_pk +
// shfl_xor(32) pair exchange (no LDS round-trip). Defer-max THR=8.

#define VKP 72
#define VSWZ(r, c) ((r) * VKP + ((c) ^ ((((r) >> 3) & 7) << 3)))

__global__ __launch_bounds__(256, 2) void k_attn(const unsigned short* __restrict__ qkv,
                                                 unsigned short* __restrict__ zb) {
  __shared__ __align__(16) unsigned short Ks[64 * 64];   // linear, gload16, src pre-swizzled chunk^=(row&7)
  __shared__ __align__(16) unsigned short Vt[64 * VKP];  // V transposed [d][kv], XOR-swizzled
  __shared__ float Lb[4][32];
  int tid = threadIdx.x;
  int lane = tid & 63, w = tid >> 6;
  int l31 = lane & 31, h5 = lane >> 5;
  int qt = 15 - blockIdx.x;            // heavy blocks dispatch first
  int bh = blockIdx.y;
  int b = bh >> 4, h = bh & 15;
  int qw = qt * 128 + w * 32;
  const size_t rowbase = (size_t)b * SEQL;
  int qg = qw + l31;

  // Q as B-fragments: B[d][q], lane: q=l31, d-window = ds*16 + h5*8 + 0..7
  bf8 qf[4];
  #pragma unroll
  for (int ds = 0; ds < 4; ds++)
    qf[ds] = *(const bf8*)(&qkv[(rowbase + qg) * NQKV + h * DHEAD + ds * 16 + h5 * 8]);

  f16v zacc0 = {}, zacc1 = {};
  float m = -1e30f, lsum = 0.f;

  int sr = tid >> 3;                       // staging row (+ it*32)
  int scc = ((tid & 7) ^ (sr & 7)) * 8;    // pre-swizzled source col (elements)

  int nkv = 2 * qt + 2;
  for (int tt = 0; tt < nkv; tt++) {
    int kv0 = tt * 64;
    // stage K: global_load_lds, linear dest, swizzled source
    #pragma unroll
    for (int it = 0; it < 2; it++)
      gload16(&qkv[(rowbase + kv0 + it * 32 + sr) * NQKV + DMODEL + h * DHEAD + scc],
              &Ks[(it * 256 + w * 64) * 8]);
    // stage V transposed (scatter, swizzled)
    #pragma unroll
    for (int cc = 0; cc < 2; cc++) {
      int c = tid + cc * 256;
      int kv = c >> 3, dc = (c & 7) * 8;
      int4 vvi = *(const int4*)(&qkv[(rowbase + kv0 + kv) * NQKV + 2 * DMODEL + h * DHEAD + dc]);
      const unsigned short* vv = (const unsigned short*)&vvi;
      #pragma unroll
      for (int i2 = 0; i2 < 8; i2++) Vt[VSWZ(dc + i2, kv)] = vv[i2];
    }
    __syncthreads();
    #pragma unroll
    for (int t32 = 0; t32 < 2; t32++) {
      int kb = kv0 + t32 * 32;
      if (kb <= qw + 31) {               // wave-uniform: skip fully-masked subtiles
        // S^T[k][q] = K-tile . Q^T : 4 MFMA over d
        f16v sa = {};
        int ar = t32 * 32 + l31;
        #pragma unroll
        for (int ds = 0; ds < 4; ds++) {
          bf8 kf = *(const bf8*)(&Ks[ar * 64 + (((ds * 2 + h5) ^ (ar & 7)) * 8)]);
          sa = mfma32(kf, qf[ds], sa);
        }
        // scale + causal mask; lane's reg r holds k_local = (r&3)+8*(r>>2)+4*h5
        float p[16];
        int diffh = qg - kb - 4 * h5;
        if (kb + 31 > qw) {
          #pragma unroll
          for (int r = 0; r < 16; r++) {
            int kc4 = (r & 3) + 8 * (r >> 2);
            p[r] = (kc4 > diffh) ? -1e30f : sa[r] * 0.125f;
          }
        } else {
          #pragma unroll
          for (int r = 0; r < 16; r++) p[r] = sa[r] * 0.125f;
        }
        // row max: in-lane tree + pair exchange
        float pmax = p[0];
        #pragma unroll
        for (int r = 1; r < 16; r++) pmax = fmaxf(pmax, p[r]);
        pmax = fmaxf(pmax, __shfl_xor(pmax, 32));
        // defer-max: rescale only when max grew past THR=8
        if (!__all(pmax - m <= 8.0f)) {
          float mn = fmaxf(m, pmax);
          float al = __expf(m - mn);
          Lb[w][l31] = al;                // broadcast alpha to reg-row domain
          m = mn;
          lsum *= al;
          #pragma unroll
          for (int r = 0; r < 16; r++) {
            float alr = Lb[w][(r & 3) + 8 * (r >> 2) + 4 * h5];
            zacc0[r] *= alr;
            zacc1[r] *= alr;
          }
        }
        // exp + row sum
        float ps = 0.f;
        #pragma unroll
        for (int r = 0; r < 16; r++) { p[r] = __expf(p[r] - m); ps += p[r]; }
        ps += __shfl_xor(ps, 32);
        lsum += ps;
        // P (lane-q domain) -> PV A-frags (reg-q domain) via cvt_pk + pair shfl
        unsigned X1 = cvtpk(p[0], p[1]),   Y1 = cvtpk(p[4], p[5]);
        unsigned X2 = cvtpk(p[2], p[3]),   Y2 = cvtpk(p[6], p[7]);
        unsigned X3 = cvtpk(p[8], p[9]),   Y3 = cvtpk(p[12], p[13]);
        unsigned X4 = cvtpk(p[10], p[11]), Y4 = cvtpk(p[14], p[15]);
        unsigned Xs1 = __shfl_xor((int)X1, 32), Ys1 = __shfl_xor((int)Y1, 32);
        unsigned Xs2 = __shfl_xor((int)X2, 32), Ys2 = __shfl_xor((int)Y2, 32);
        unsigned Xs3 = __shfl_xor((int)X3, 32), Ys3 = __shfl_xor((int)Y3, 32);
        unsigned Xs4 = __shfl_xor((int)X4, 32), Ys4 = __shfl_xor((int)Y4, 32);
        union { bf8 v; unsigned u[4]; } pa0, pa1;
        pa0.u[0] = h5 ? Ys1 : X1;  pa0.u[2] = h5 ? Y1 : Xs1;
        pa0.u[1] = h5 ? Ys2 : X2;  pa0.u[3] = h5 ? Y2 : Xs2;
        pa1.u[0] = h5 ? Ys3 : X3;  pa1.u[2] = h5 ? Y3 : Xs3;
        pa1.u[1] = h5 ? Ys4 : X4;  pa1.u[3] = h5 ? Y4 : Xs4;
        // PV: Z[q][d] += P[q][k] . V[k][d]; B-frag = Vt[d-row][k cont]
        #pragma unroll
        for (int e = 0; e < 2; e++) {
          int vr = e * 32 + l31;
          int fv = ((vr >> 3) & 7) << 3;
          f16v& zr = e ? zacc1 : zacc0;
          #pragma unroll
          for (int ks = 0; ks < 2; ks++) {
            bf8 vb = *(const bf8*)(&Vt[vr * VKP + ((t32 * 32 + ks * 16 + h5 * 8) ^ fv)]);
            zr = mfma32(ks ? pa1.v : pa0.v, vb, zr);
          }
        }
      }
    }
    __syncthreads();
  }
  // epilogue: broadcast 1/l to reg-row domain, write z
  Lb[w][l31] = 1.0f / lsum;
  #pragma unroll
  for (int r = 0; r < 16; r++) {
    int crow = (r & 3) + 8 * (r >> 2) + 4 * h5;
    float inv = Lb[w][crow];
    size_t row = rowbase + qw + crow;
    zb[row * DMODEL + h * DHEAD + l31] = f2b(zacc0[r] * inv);
    zb[row * DMODEL + h * DHEAD + 32 + l31] = f2b(zacc1[r] * inv);
  }
}

// ---------------- launch ----------------

extern "C" void kernel_launch(void* const* d_in, const int* in_sizes, int n_in,
                              void* d_out, int out_size, void* d_ws, size_t ws_size,
                              hipStream_t stream) {
  const float* x  = (const float*)d_in[0];
  const float* Wq = (const float*)d_in[1];
  const float* bq = (const float*)d_in[2];
  const float* Wk = (const float*)d_in[3];
  const float* bk = (const float*)d_in[4];
  const float* Wv = (const float*)d_in[5];
  const float* bv = (const float*)d_in[6];
  const float* Wo = (const float*)d_in[7];
  const float* bo = (const float*)d_in[8];

  char* ws = (char*)d_ws;
  // layout: xb 8MiB | wqkvt 6MiB | biasq 16KiB | qkv 24MiB | wot 2MiB  (~40MiB)
  unsigned short* xb    = (unsigned short*)(ws);
  unsigned short* wqkvt = (unsigned short*)(ws + 8388608);
  float*          biasq = (float*)(ws + 8388608 + 6291456);
  unsigned short* qkv   = (unsigned short*)(ws + 8388608 + 6291456 + 16384);
  unsigned short* wot   = (unsigned short*)(ws + 8388608 + 6291456 + 16384 + 25165824);
  unsigned short* zbuf  = xb;  // alias: xb dead after GEMM1 (stream-ordered)

  k_f32_to_bf16<<<(MROWS * DMODEL / 4 + 255) / 256, 256, 0, stream>>>(x, xb, MROWS * DMODEL / 4);
  k_pack_wqkv<<<dim3(16, 16, 3), 256, 0, stream>>>(Wq, Wk, Wv, bq, bk, bv, wqkvt, biasq);
  k_pack_wo<<<dim3(16, 16), 256, 0, stream>>>(Wo, wot);
  k_gemm_bt<NQKV, DMODEL, false><<<dim3(32, 24), 256, 0, stream>>>(xb, wqkvt, biasq, qkv);
  k_attn<<<dim3(16, 32), 256, 0, stream>>>(qkv, zbuf);
  k_gemm_bt<DMODEL, DMODEL, true><<<dim3(32, 8), 256, 0, stream>>>(zbuf, wot, bo, (float*)d_out);
}

// Round 11
// 220.772 us; speedup vs baseline: 1.4182x; 1.0515x over previous
//
#include <hip/hip_runtime.h>
#include <math.h>

#define DMODEL 1024
#define NHEADS 16
#define DHEAD 64
#define SEQL 2048
#define NBATCH 2
#define MROWS (NBATCH*SEQL)   // 4096
#define QKS 2048              // qkv2 row stride (q|k)

typedef __attribute__((ext_vector_type(8))) short bf8;
typedef __attribute__((ext_vector_type(4))) float f4;
typedef __attribute__((ext_vector_type(16))) float f16v;

__device__ __forceinline__ unsigned short f2b(float f) {
  union { float f; unsigned int u; } v; v.f = f;
  unsigned int r = v.u + 0x7FFFu + ((v.u >> 16) & 1u);
  return (unsigned short)(r >> 16);
}

__device__ __forceinline__ f4 mfma16(bf8 a, bf8 b, f4 c) {
  return __builtin_amdgcn_mfma_f32_16x16x32_bf16(a, b, c, 0, 0, 0);
}

__device__ __forceinline__ f16v mfma32(bf8 a, bf8 b, f16v c) {
  return __builtin_amdgcn_mfma_f32_32x32x16_bf16(a, b, c, 0, 0, 0);
}

__device__ __forceinline__ unsigned cvtpk(float lo, float hi) {
  unsigned r;
  asm("v_cvt_pk_bf16_f32 %0, %1, %2" : "=v"(r) : "v"(lo), "v"(hi));
  return r;
}

__device__ __forceinline__ void gload16(const void* g, void* l) {
  __builtin_amdgcn_global_load_lds(
      (const __attribute__((address_space(1))) unsigned int*)g,
      (__attribute__((address_space(3))) unsigned int*)l, 16, 0, 0);
}

// ---------------- pack kernels ----------------

__global__ __launch_bounds__(256) void k_f32_to_bf16(const float* __restrict__ in,
                                                     unsigned short* __restrict__ out, int n4) {
  int i = blockIdx.x * 256 + threadIdx.x;
  if (i < n4) {
    float4 v = ((const float4*)in)[i];
    ushort4 o;
    o.x = f2b(v.x); o.y = f2b(v.y); o.z = f2b(v.z); o.w = f2b(v.w);
    ((ushort4*)out)[i] = o;
  }
}

// W_Q/W_K/W_V [h][d][e] -> Wt[c][d] (c = p*1024 + h*64 + e), bf16, row-major over d
__global__ __launch_bounds__(256) void k_pack_wqkv(
    const float* __restrict__ Wq, const float* __restrict__ Wk, const float* __restrict__ Wv,
    const float* __restrict__ bq, const float* __restrict__ bk, const float* __restrict__ bv,
    unsigned short* __restrict__ Wt, float* __restrict__ biasq) {
  __shared__ float tile[64][65];
  int tid = threadIdx.x;
  int dt = blockIdx.x, h = blockIdx.y, p = blockIdx.z;
  const float* W = (p == 0) ? Wq : ((p == 1) ? Wk : Wv);
  #pragma unroll
  for (int j = 0; j < 16; j++) {
    int idx = tid + j * 256;
    int dd = idx >> 6, e = idx & 63;
    tile[dd][e] = W[(size_t)(h * DMODEL + dt * 64 + dd) * DHEAD + e];
  }
  __syncthreads();
  #pragma unroll
  for (int j = 0; j < 16; j++) {
    int idx = tid + j * 256;
    int e = idx >> 6, dd = idx & 63;
    Wt[(size_t)(p * DMODEL + h * 64 + e) * DMODEL + dt * 64 + dd] = f2b(tile[dd][e]);
  }
  if (dt == 0 && tid < 64) {
    const float* bsel = (p == 0) ? bq : ((p == 1) ? bk : bv);
    biasq[p * DMODEL + h * 64 + tid] = bsel[h * 64 + tid];
  }
}

// W_O [he][dm] -> Wot[dm][he] bf16
__global__ __launch_bounds__(256) void k_pack_wo(const float* __restrict__ Wo,
                                                 unsigned short* __restrict__ Wot) {
  __shared__ float tile[64][65];
  int tid = threadIdx.x;
  int het = blockIdx.x, dmt = blockIdx.y;
  #pragma unroll
  for (int j = 0; j < 16; j++) {
    int idx = tid + j * 256;
    int r = idx >> 6, c = idx & 63;
    tile[r][c] = Wo[(size_t)(het * 64 + r) * DMODEL + dmt * 64 + c];
  }
  __syncthreads();
  #pragma unroll
  for (int j = 0; j < 16; j++) {
    int idx = tid + j * 256;
    int rr = idx >> 6, cc = idx & 63;
    Wot[(size_t)(dmt * 64 + rr) * DMODEL + het * 64 + cc] = f2b(tile[cc][rr]);
  }
}

// ---------------- GEMM: C[4096][N] = A[4096][K] * Bt[N][K]^T + bias ----------------
// MODE 0: bf16 row-major [M][N]; MODE 1: f32 row-major; MODE 2: V-transpose
// epilogue -> vT[(b*1024 + col)][2048] bf16 (col = h*64+e, s = row&2047).

template<int N, int K, int MODE>
__global__ __launch_bounds__(256) void k_gemm_bt(
    const unsigned short* __restrict__ A, const unsigned short* __restrict__ Bt,
    const float* __restrict__ bias, void* __restrict__ Cp) {
  __shared__ unsigned short As[128 * 64];
  __shared__ unsigned short Bs[128 * 64];
  int tid = threadIdx.x;
  int lane = tid & 63, w = tid >> 6;
  int wr = w >> 1, wc = w & 1;
  int lr = lane & 15, lg = lane >> 4;
  int m0 = blockIdx.x * 128, n0 = blockIdx.y * 128;
  int srow = w * 8 + (lane >> 3);               // + it*32
  int scol = ((lane & 7) ^ (lane >> 3)) * 8;    // row&7 == lane>>3 here
  f4 acc[4][4] = {};
  for (int k0 = 0; k0 < K; k0 += 64) {
    #pragma unroll
    for (int it = 0; it < 4; it++) {
      int row = it * 32 + srow;
      gload16(&A[(size_t)(m0 + row) * K + k0 + scol], &As[(it * 256 + w * 64) * 8]);
      gload16(&Bt[(size_t)(n0 + row) * K + k0 + scol], &Bs[(it * 256 + w * 64) * 8]);
    }
    __syncthreads();
    #pragma unroll
    for (int kk = 0; kk < 2; kk++) {
      bf8 af[4], bfv[4];
      #pragma unroll
      for (int i = 0; i < 4; i++) {
        int ra = wr * 64 + i * 16 + lr;
        int rb = wc * 64 + i * 16 + lr;
        af[i]  = *(const bf8*)(&As[ra * 64 + (((kk * 4 + lg) ^ (ra & 7)) * 8)]);
        bfv[i] = *(const bf8*)(&Bs[rb * 64 + (((kk * 4 + lg) ^ (rb & 7)) * 8)]);
      }
      #pragma unroll
      for (int i = 0; i < 4; i++)
        #pragma unroll
        for (int j = 0; j < 4; j++)
          acc[i][j] = mfma16(af[i], bfv[j], acc[i][j]);
    }
    __syncthreads();
  }
  if (MODE == 2) {
    #pragma unroll
    for (int i = 0; i < 4; i++) {
      int row0 = m0 + wr * 64 + i * 16 + lg * 4;
      int b = row0 >> 11, s0 = row0 & 2047;
      #pragma unroll
      for (int j = 0; j < 4; j++) {
        int col = n0 + wc * 64 + j * 16 + lr;
        float bv = bias[col];
        ushort4 o;
        o.x = f2b(acc[i][j][0] + bv);
        o.y = f2b(acc[i][j][1] + bv);
        o.z = f2b(acc[i][j][2] + bv);
        o.w = f2b(acc[i][j][3] + bv);
        *(ushort4*)((unsigned short*)Cp + (size_t)(b * 1024 + col) * 2048 + s0) = o;
      }
    }
  } else {
    #pragma unroll
    for (int i = 0; i < 4; i++)
      #pragma unroll
      for (int j = 0; j < 4; j++) {
        int col = n0 + wc * 64 + j * 16 + lr;
        float bv = bias[col];
        #pragma unroll
        for (int r = 0; r < 4; r++) {
          int row = m0 + wr * 64 + i * 16 + lg * 4 + r;
          float v = acc[i][j][r] + bv;
          if (MODE == 1) ((float*)Cp)[(size_t)row * N + col] = v;
          else ((unsigned short*)Cp)[(size_t)row * N + col] = f2b(v);
        }
      }
  }
}

// ---------------- flash attention (swapped-QK^T, dbuf staging, pure gload16) ----
// qkv2: [4096][2048] bf16 (q cols 0..1023, k cols 1024..2047)
// vT  : [2048][2048] bf16 (row = b*1024 + h*64 + d, col = s)
// zb  : [4096][1024] bf16
// Balance: qt = (b ? bx : 15-bx) so CU-paired blocks (i, i+256) get
// complementary work: 36 tile-iterations per CU uniformly.

__global__ __launch_bounds__(256) void k_attn(const unsigned short* __restrict__ qkv2,
                                              const unsigned short* __restrict__ vT,
                                              unsigned short* __restrict__ zb) {
  __shared__ __align__(16) unsigned short Ks[2][64 * 64];
  __shared__ __align__(16) unsigned short Vs[2][64 * 64];
  __shared__ float Lb[4][32];
  int tid = threadIdx.x;
  int lane = tid & 63, w = tid >> 6;
  int l31 = lane & 31, h5 = lane >> 5;
  int bx = blockIdx.x, by = blockIdx.y;
  int b = by >> 4, h = by & 15;
  int qt = b ? bx : (15 - bx);
  int qw = qt * 128 + w * 32;
  const size_t rowbase = (size_t)b * SEQL;
  int qg = qw + l31;

  // Q as B-fragments: lane q=l31, d-window = ds*16 + h5*8
  bf8 qf[4];
  #pragma unroll
  for (int ds = 0; ds < 4; ds++)
    qf[ds] = *(const bf8*)(&qkv2[(rowbase + qg) * QKS + h * DHEAD + ds * 16 + h5 * 8]);

  const unsigned short* Kg = qkv2 + DMODEL + h * DHEAD;            // + row*QKS
  const unsigned short* Vg = vT + (size_t)(b * 1024 + h * DHEAD) * SEQL;  // + d*SEQL

  f16v zacc0 = {}, zacc1 = {};
  float m = -1e30f, lsum = 0.f;

  int sr = tid >> 3;                       // staging row (+ it*32)
  int scc = ((tid & 7) ^ (sr & 7)) * 8;    // pre-swizzled source col (elements)

  int nkv = 2 * qt + 2;
  // prologue: stage tile 0 into buf 0
  #pragma unroll
  for (int it = 0; it < 2; it++) {
    gload16(&Kg[(rowbase + it * 32 + sr) * QKS + scc], &Ks[0][(it * 256 + w * 64) * 8]);
    gload16(&Vg[(size_t)(it * 32 + sr) * SEQL + scc], &Vs[0][(it * 256 + w * 64) * 8]);
  }
  __syncthreads();
  int buf = 0;
  for (int tt = 0; tt < nkv; tt++) {
    // issue next-tile stage early (hidden under compute)
    if (tt + 1 < nkv) {
      int kn = (tt + 1) * 64;
      #pragma unroll
      for (int it = 0; it < 2; it++) {
        gload16(&Kg[(rowbase + kn + it * 32 + sr) * QKS + scc], &Ks[buf ^ 1][(it * 256 + w * 64) * 8]);
        gload16(&Vg[(size_t)(it * 32 + sr) * SEQL + kn + scc], &Vs[buf ^ 1][(it * 256 + w * 64) * 8]);
      }
    }
    int kv0 = tt * 64;
    const unsigned short* KsB = &Ks[buf][0];
    const unsigned short* VsB = &Vs[buf][0];
    #pragma unroll
    for (int t32 = 0; t32 < 2; t32++) {
      int kb = kv0 + t32 * 32;
      if (kb <= qw + 31) {               // wave-uniform: skip fully-masked subtiles
        // S^T[k][q] = K-tile . Q^T : 4 MFMA over d
        f16v sa = {};
        int ar = t32 * 32 + l31;
        #pragma unroll
        for (int ds = 0; ds < 4; ds++) {
          bf8 kf = *(const bf8*)(&KsB[ar * 64 + (((ds * 2 + h5) ^ (ar & 7)) * 8)]);
          sa = mfma32(kf, qf[ds], sa);
        }
        // scale + causal mask; reg r holds k_local = (r&3)+8*(r>>2)+4*h5
        float p[16];
        int diffh = qg - kb - 4 * h5;
        if (kb + 31 > qw) {
          #pragma unroll
          for (int r = 0; r < 16; r++) {
            int kc4 = (r & 3) + 8 * (r >> 2);
            p[r] = (kc4 > diffh) ? -1e30f : sa[r] * 0.125f;
          }
        } else {
          #pragma unroll
          for (int r = 0; r < 16; r++) p[r] = sa[r] * 0.125f;
        }
        // row max: in-lane tree + pair exchange
        float pmax = p[0];
        #pragma unroll
        for (int r = 1; r < 16; r++) pmax = fmaxf(pmax, p[r]);
        pmax = fmaxf(pmax, __shfl_xor(pmax, 32));
        // defer-max: rescale only when max grew past THR=8
        if (!__all(pmax - m <= 8.0f)) {
          float mn = fmaxf(m, pmax);
          float al = __expf(m - mn);
          Lb[w][l31] = al;                // broadcast alpha to reg-row domain
          m = mn;
          lsum *= al;
          #pragma unroll
          for (int r = 0; r < 16; r++) {
            float alr = Lb[w][(r & 3) + 8 * (r >> 2) + 4 * h5];
            zacc0[r] *= alr;
            zacc1[r] *= alr;
          }
        }
        // exp + row sum
        float ps = 0.f;
        #pragma unroll
        for (int r = 0; r < 16; r++) { p[r] = __expf(p[r] - m); ps += p[r]; }
        ps += __shfl_xor(ps, 32);
        lsum += ps;
        // P (lane-q domain) -> PV A-frags (reg-q domain) via cvt_pk + pair shfl
        unsigned X1 = cvtpk(p[0], p[1]),   Y1 = cvtpk(p[4], p[5]);
        unsigned X2 = cvtpk(p[2], p[3]),   Y2 = cvtpk(p[6], p[7]);
        unsigned X3 = cvtpk(p[8], p[9]),   Y3 = cvtpk(p[12], p[13]);
        unsigned X4 = cvtpk(p[10], p[11]), Y4 = cvtpk(p[14], p[15]);
        unsigned Xs1 = __shfl_xor((int)X1, 32), Ys1 = __shfl_xor((int)Y1, 32);
        unsigned Xs2 = __shfl_xor((int)X2, 32), Ys2 = __shfl_xor((int)Y2, 32);
        unsigned Xs3 = __shfl_xor((int)X3, 32), Ys3 = __shfl_xor((int)Y3, 32);
        unsigned Xs4 = __shfl_xor((int)X4, 32), Ys4 = __shfl_xor((int)Y4, 32);
        union { bf8 v; unsigned u[4]; } pa0, pa1;
        pa0.u[0] = h5 ? Ys1 : X1;  pa0.u[2] = h5 ? Y1 : Xs1;
        pa0.u[1] = h5 ? Ys2 : X2;  pa0.u[3] = h5 ? Y2 : Xs2;
        pa1.u[0] = h5 ? Ys3 : X3;  pa1.u[2] = h5 ? Y3 : Xs3;
        pa1.u[1] = h5 ? Ys4 : X4;  pa1.u[3] = h5 ? Y4 : Xs4;
        // PV: Z[q][d] += P[q][k] . V[k][d]; B-frag = Vs[d][k cont]
        #pragma unroll
        for (int e = 0; e < 2; e++) {
          int vr = e * 32 + l31;
          f16v& zr = e ? zacc1 : zacc0;
          #pragma unroll
          for (int ks = 0; ks < 2; ks++) {
            bf8 vb = *(const bf8*)(&VsB[vr * 64 + (((t32 * 4 + ks * 2 + h5) ^ (vr & 7)) * 8)]);
            zr = mfma32(ks ? pa1.v : pa0.v, vb, zr);
          }
        }
      }
    }
    __syncthreads();
    buf ^= 1;
  }
  // epilogue: broadcast 1/l to reg-row domain, write z
  Lb[w][l31] = 1.0f / lsum;
  #pragma unroll
  for (int r = 0; r < 16; r++) {
    int crow = (r & 3) + 8 * (r >> 2) + 4 * h5;
    float inv = Lb[w][crow];
    size_t row = rowbase + qw + crow;
    zb[row * DMODEL + h * DHEAD + l31] = f2b(zacc0[r] * inv);
    zb[row * DMODEL + h * DHEAD + 32 + l31] = f2b(zacc1[r] * inv);
  }
}

// ---------------- launch ----------------

extern "C" void kernel_launch(void* const* d_in, const int* in_sizes, int n_in,
                              void* d_out, int out_size, void* d_ws, size_t ws_size,
                              hipStream_t stream) {
  const float* x  = (const float*)d_in[0];
  const float* Wq = (const float*)d_in[1];
  const float* bq = (const float*)d_in[2];
  const float* Wk = (const float*)d_in[3];
  const float* bk = (const float*)d_in[4];
  const float* Wv = (const float*)d_in[5];
  const float* bv = (const float*)d_in[6];
  const float* Wo = (const float*)d_in[7];
  const float* bo = (const float*)d_in[8];

  char* ws = (char*)d_ws;
  // layout: xb 8MiB | wqkvt 6MiB | biasq 16KiB | qkv2 16MiB | vT 8MiB | wot 2MiB
  unsigned short* xb    = (unsigned short*)(ws);
  unsigned short* wqkvt = (unsigned short*)(ws + 8388608);
  float*          biasq = (float*)(ws + 14680064);
  unsigned short* qkv2  = (unsigned short*)(ws + 14696448);
  unsigned short* vT    = (unsigned short*)(ws + 31473664);
  unsigned short* wot   = (unsigned short*)(ws + 39862272);
  unsigned short* zbuf  = xb;  // alias: xb dead after GEMM1 (stream-ordered)

  k_f32_to_bf16<<<(MROWS * DMODEL / 4 + 255) / 256, 256, 0, stream>>>(x, xb, MROWS * DMODEL / 4);
  k_pack_wqkv<<<dim3(16, 16, 3), 256, 0, stream>>>(Wq, Wk, Wv, bq, bk, bv, wqkvt, biasq);
  k_pack_wo<<<dim3(16, 16), 256, 0, stream>>>(Wo, wot);
  // QK projection -> qkv2 [4096][2048]
  k_gemm_bt<QKS, DMODEL, 0><<<dim3(32, 16), 256, 0, stream>>>(xb, wqkvt, biasq, qkv2);
  // V projection -> vT [2048][2048] (transposed epilogue)
  k_gemm_bt<DMODEL, DMODEL, 2><<<dim3(32, 8), 256, 0, stream>>>(
      xb, wqkvt + (size_t)2048 * DMODEL, biasq + 2048, vT);
  k_attn<<<dim3(16, 32), 256, 0, stream>>>(qkv2, vT, zbuf);
  k_gemm_bt<DMODEL, DMODEL, 1><<<dim3(32, 8), 256, 0, stream>>>(zbuf, wot, bo, (float*)d_out);
}